// Round 13
// baseline (360.484 us; speedup 1.0000x reference)
//
#include <hip/hip_runtime.h>

typedef unsigned short ushort_t;
typedef __attribute__((ext_vector_type(8))) __bf16 bf16x8;
typedef __attribute__((ext_vector_type(8))) unsigned short ushort8;
typedef __attribute__((ext_vector_type(4))) unsigned short ushort4_t;
typedef __attribute__((ext_vector_type(4))) float floatx4;

__device__ inline unsigned short f2bf(float f) {
  union { float f; unsigned u; } x; x.f = f;
  return (unsigned short)((x.u + 0x7FFFu + ((x.u >> 16) & 1u)) >> 16);
}
__device__ inline float bf2f(unsigned short v) {
  union { unsigned u; float f; } x; x.u = (unsigned)v << 16;
  return x.f;
}

__device__ inline void bar() {
  asm volatile("" ::: "memory");
  __builtin_amdgcn_s_barrier();
  asm volatile("" ::: "memory");
}
#define WAITV0 asm volatile("s_waitcnt vmcnt(0)" ::: "memory")

// ---- fused: tens fp32 -> Xbf + XT; per-block colsum partials; weight plane --
__global__ void cvt_tr(const float* __restrict__ tens, ushort_t* __restrict__ Xbf,
                       ushort_t* __restrict__ XT, float* __restrict__ spart,
                       const float* __restrict__ Wk, ushort_t* __restrict__ Wkbf,
                       const float* __restrict__ Wv, ushort_t* __restrict__ Wvbf) {
  int t = threadIdx.x;
  if (blockIdx.z == 4) {
    int flat = blockIdx.x + 16 * blockIdx.y;  // 0..1023
    const float* in; ushort_t* out;
    if (flat < 512) { in = Wk; out = Wkbf; } else { in = Wv; out = Wvbf; flat -= 512; }
    int i = (flat * 256 + t) * 8;
    const float4* p = (const float4*)(in + i);
    float4 x = p[0], y = p[1];
    ushort8 o;
    o[0] = f2bf(x.x); o[1] = f2bf(x.y); o[2] = f2bf(x.z); o[3] = f2bf(x.w);
    o[4] = f2bf(y.x); o[5] = f2bf(y.y); o[6] = f2bf(y.z); o[7] = f2bf(y.w);
    *(ushort8*)(out + i) = o;
    return;
  }
  int b = blockIdx.z;
  int d0 = blockIdx.x * 64;  // 16
  int n0 = blockIdx.y * 64;  // 64
  __shared__ ushort_t sT[64 * 72];
  int nl = t >> 2, c16 = (t & 3) * 16;
  const float* src = tens + ((long)b << 22) + (long)(n0 + nl) * 1024 + d0 + c16;
  ushort8 o0, o1;
#pragma unroll
  for (int j = 0; j < 2; ++j) {
    float4 v0 = *(const float4*)(src + j * 8);
    float4 v1 = *(const float4*)(src + j * 8 + 4);
    ushort8 o;
    o[0] = f2bf(v0.x); o[1] = f2bf(v0.y); o[2] = f2bf(v0.z); o[3] = f2bf(v0.w);
    o[4] = f2bf(v1.x); o[5] = f2bf(v1.y); o[6] = f2bf(v1.z); o[7] = f2bf(v1.w);
#pragma unroll
    for (int i = 0; i < 8; ++i) sT[(c16 + j * 8 + i) * 72 + nl] = o[i];
    if (j == 0) o0 = o; else o1 = o;
  }
  ushort_t* xdst = Xbf + ((long)b << 22) + (long)(n0 + nl) * 1024 + d0 + c16;
  *(ushort8*)xdst = o0;
  *(ushort8*)(xdst + 8) = o1;
  __syncthreads();
  int dl = t >> 2, n16 = (t & 3) * 16;
  ushort8 t0 = *(const ushort8*)(sT + dl * 72 + n16);
  ushort8 t1 = *(const ushort8*)(sT + dl * 72 + n16 + 8);
  ushort_t* dst = XT + ((long)b << 22) + (long)(d0 + dl) * 4096 + n0 + n16;
  *(ushort8*)dst = t0;
  *(ushort8*)(dst + 8) = t1;
  float ps = 0.f;
#pragma unroll
  for (int i = 0; i < 8; ++i) ps += bf2f(t0[i]) + bf2f(t1[i]);
  ps += __shfl_xor(ps, 1);
  ps += __shfl_xor(ps, 2);
  if ((t & 3) == 0) spart[(((long)b << 6) + blockIdx.y) * 1024 + d0 + dl] = ps;
}

// ---------------- async global->LDS helper ----------------------------------
__device__ inline void gload_lds16(const void* g, void* l) {
  __builtin_amdgcn_global_load_lds(
      (const __attribute__((address_space(1))) unsigned int*)g,
      (__attribute__((address_space(3))) unsigned int*)l, 16, 0, 0);
}

// ---------------- 256x256-tile NT GEMM, minimal-sync, swapped epilogue ------
// 8 waves (2M x 4N), wave tile 128x64, acc[8][4]. BK=64; 2dbuf x 64KB.
// Per K-tile: {STAGE(t+1 -> buf^1); 24 ds_read_b128 + 64 MFMA; vmcnt(0); bar}.
// (row&7) swizzle: inverse on GLOBAL source (linear gload dest), forward on
// ds_read -- measured 0 bank conflicts. MFMA operands SWAPPED
// (mfma(bfr, af)): lane holds 4 consecutive n at fixed m -> float4 C-stores +
// float4 bias loads (round-8-verified mapping; fixes 79->66MB write ampl.).
template <int K>
__global__ __launch_bounds__(512, 2) void gemm256(
    const ushort_t* __restrict__ A, const ushort_t* __restrict__ Bm,
    const float* __restrict__ bias, float* __restrict__ C,
    int N, long sA_, long sB_, long sBias_, long sC_) {
  const int NT = K / 64;
  int gx = gridDim.x, gxy = gridDim.x * gridDim.y;
  int flat = blockIdx.x + gx * blockIdx.y + gxy * blockIdx.z;
  int total = gxy * gridDim.z;
  int per = total >> 3;
  int nf = (flat & 7) * per + (flat >> 3);
  int bz = nf / gxy; int rem = nf - bz * gxy;
  int by = rem / gx; int bx = rem - by * gx;

  A += (long)bz * sA_; Bm += (long)bz * sB_; C += (long)bz * sC_;
  bias += (long)bz * sBias_;

  __shared__ ushort_t sA[2][16384];  // [buf][half(8192) | row*64 | col]
  __shared__ ushort_t sB[2][16384];

  int t = threadIdx.x;
  int w = t >> 6, l = t & 63;
  int wy = w >> 2, wx = w & 3;            // 2M x 4N wave grid
  int quad = l >> 4, m16 = l & 15;
  int mBase = by * 256, nBase = bx * 256;

  // ---- staging: lane covers row rp, 16B block p8; source block pre-swizzled
  int rp = w * 8 + (l >> 3);                       // 0..63 within group
  int p8 = l & 7;
  int ce = ((p8 ^ (rp & 7)) << 3);                 // inverse-swizzled src col
  const ushort_t* gAp[4]; const ushort_t* gBp[4];  // [half*2+g]
#pragma unroll
  for (int h = 0; h < 2; ++h)
#pragma unroll
    for (int g = 0; g < 2; ++g) {
      gAp[h * 2 + g] = A + (long)(mBase + h * 128 + g * 64 + rp) * K + ce;
      gBp[h * 2 + g] = Bm + (long)(nBase + h * 128 + g * 64 + rp) * K + ce;
    }

  int swz3 = m16 & 7;                              // read-side XOR key
  int aBase = wy * 8192 + m16 * 64;
  int bBase = (wx >> 1) * 8192 + ((wx & 1) * 64 + m16) * 64;

  floatx4 acc[8][4] = {};

  auto STAGE = [&](int kt, int buf) {
    int ko = kt * 64;
#pragma unroll
    for (int g = 0; g < 2; ++g) {
      gload_lds16(gAp[g] + ko,     sA[buf] + g * 4096 + w * 512);
      gload_lds16(gAp[2 + g] + ko, sA[buf] + 8192 + g * 4096 + w * 512);
      gload_lds16(gBp[g] + ko,     sB[buf] + g * 4096 + w * 512);
      gload_lds16(gBp[2 + g] + ko, sB[buf] + 8192 + g * 4096 + w * 512);
    }
  };

  STAGE(0, 0);
  WAITV0;
  bar();
  for (int kt = 0; kt < NT; ++kt) {
    int buf = kt & 1;
    if (kt + 1 < NT) STAGE(kt + 1, buf ^ 1);  // 8 loads fly under 64 MFMAs
    __builtin_amdgcn_sched_barrier(0);        // keep stage issue first
    const ushort_t* pa = sA[buf];
    const ushort_t* pb = sB[buf];
    __builtin_amdgcn_s_setprio(1);
#pragma unroll
    for (int ks = 0; ks < 2; ++ks) {
      int ct = (((ks * 4 + quad) ^ swz3) << 3);
      bf16x8 bfr[4];
#pragma unroll
      for (int ni = 0; ni < 4; ++ni)
        bfr[ni] = *(const bf16x8*)(pb + bBase + ni * 16 * 64 + ct);
#pragma unroll
      for (int mg = 0; mg < 2; ++mg) {
        bf16x8 af[4];
#pragma unroll
        for (int i = 0; i < 4; ++i)
          af[i] = *(const bf16x8*)(pa + aBase + (mg * 4 + i) * 16 * 64 + ct);
#pragma unroll
        for (int i = 0; i < 4; ++i)
#pragma unroll
          for (int ni = 0; ni < 4; ++ni)
            acc[mg * 4 + i][ni] = __builtin_amdgcn_mfma_f32_16x16x32_bf16(
                bfr[ni], af[i], acc[mg * 4 + i][ni], 0, 0, 0);
      }
    }
    __builtin_amdgcn_s_setprio(0);
    if (kt + 1 < NT) { WAITV0; }
    bar();
  }

  // swapped layout: col (m16) -> m; rows (quad*4+rr) -> 4 consecutive n
#pragma unroll
  for (int mi = 0; mi < 8; ++mi) {
    int m = mBase + wy * 128 + mi * 16 + m16;
    float* crow = C + (long)m * N;
#pragma unroll
    for (int ni = 0; ni < 4; ++ni) {
      int n0 = nBase + wx * 64 + ni * 16 + quad * 4;
      float4 bb = *(const float4*)(bias + n0);
      floatx4 v = acc[mi][ni];
      float4 o;
      o.x = v[0] + bb.x; o.y = v[1] + bb.y; o.z = v[2] + bb.z; o.w = v[3] + bb.w;
      *(float4*)(crow + n0) = o;
    }
  }
}

// ---------------- 64x64-tile NT GEMM, BK=64 (G + uw roles) ------------------
template <int K, bool SYM, bool UW>
__global__ void gemm64(const ushort_t* __restrict__ A, const ushort_t* __restrict__ Bm,
                       ushort_t* __restrict__ C, int N, long sA_, long sB_, long sC_,
                       const ushort_t* __restrict__ Wkbf, const ushort_t* __restrict__ Wvbf,
                       const float* __restrict__ spart, float* __restrict__ u,
                       float* __restrict__ wv_s) {
  __shared__ ushort_t sA[2][2][64 * 32];  // [buf][kk][row*32]
  __shared__ ushort_t sB[2][2][64 * 32];
  int t = threadIdx.x;

  int bz, byy, bxx;
  if (SYM) {
    int flat = blockIdx.x + gridDim.x * blockIdx.y;
    int per = (gridDim.x * gridDim.y) >> 3;
    int nf = (flat & 7) * per + (flat >> 3);
    if (UW) {
      if (nf >= 544) {
        int id = nf - 544;  // 0..31
        int b = id & 3, which = (id >> 2) & 1, chunk = id >> 3;
        const ushort_t* W = which ? Wvbf : Wkbf;
        float* o = which ? wv_s : u;
        float* ss = (float*)sA;  // 4KB alias
        float4 a4 = {0.f, 0.f, 0.f, 0.f};
        const float* sp = spart + ((long)b << 16) + t * 4;
        for (int n0 = 0; n0 < 64; ++n0) {
          float4 v = *(const float4*)(sp + n0 * 1024);
          a4.x += v.x; a4.y += v.y; a4.z += v.z; a4.w += v.w;
        }
        *(float4*)(ss + t * 4) = a4;
        __syncthreads();
        int rr = chunk * 256 + t;
        const ushort_t* row = W + (long)rr * 1024;
        float acc = 0.f;
        for (int k = 0; k < 1024; k += 8) {
          ushort8 v = *(const ushort8*)(row + k);
#pragma unroll
          for (int i = 0; i < 8; ++i) acc += bf2f(v[i]) * ss[k + i];
        }
        o[b * 1024 + rr] = acc;
        return;
      }
    }
    bz = nf / 136;
    int tri = nf - bz * 136;
    byy = (int)((__fsqrt_rn(8.0f * tri + 1.0f) - 1.0f) * 0.5f);
    while ((byy + 1) * (byy + 2) / 2 <= tri) ++byy;
    while (byy * (byy + 1) / 2 > tri) --byy;
    bxx = tri - byy * (byy + 1) / 2;  // bxx <= byy
  } else {
    int gx = gridDim.x, gxy = gridDim.x * gridDim.y;
    int flat = blockIdx.x + gx * blockIdx.y + gxy * blockIdx.z;
    int total = gxy * gridDim.z;
    int per = total >> 3;
    int nf = (flat & 7) * per + (flat >> 3);
    bz = nf / gxy; int rem = nf - bz * gxy;
    byy = rem / gx; bxx = rem - byy * gx;
  }

  A += (long)bz * sA_; Bm += (long)bz * sB_; C += (long)bz * sC_;

  int w = t >> 6, l = t & 63;
  int wy = w >> 1, wx = w & 1;
  int quad = l >> 4, m16 = l & 15;
  int mBase = byy * 64, nBase = bxx * 64;

  int r = l >> 2, pk = l & 3;
  int sCol = (pk ^ ((r >> 1) & 3)) * 8;
  int sRow = w * 16 + r;
  const ushort_t* gA = A + (long)(mBase + sRow) * K + sCol;
  const ushort_t* gB = Bm + (long)(nBase + sRow) * K + sCol;
  int lOff = w * 512;

  int swzR = (m16 >> 1) & 3;
  int aOff = (wy * 32 + m16) * 32 + (quad ^ swzR) * 8;
  int bOff = (wx * 32 + m16) * 32 + (quad ^ swzR) * 8;

  floatx4 acc[2][2] = {};
  const int NS = K / 64;

#pragma unroll
  for (int kk = 0; kk < 2; ++kk) {
    gload_lds16(gA + kk * 32, sA[0][kk] + lOff);
    gload_lds16(gB + kk * 32, sB[0][kk] + lOff);
  }
  __syncthreads();

  for (int kt = 0; kt < NS; ++kt) {
    if (kt + 1 < NS) {
      int nb = (kt + 1) & 1, ko = (kt + 1) * 64;
#pragma unroll
      for (int kk = 0; kk < 2; ++kk) {
        gload_lds16(gA + ko + kk * 32, sA[nb][kk] + lOff);
        gload_lds16(gB + ko + kk * 32, sB[nb][kk] + lOff);
      }
    }
    __builtin_amdgcn_sched_barrier(0);
    int cb = kt & 1;
#pragma unroll
    for (int kk = 0; kk < 2; ++kk) {
      bf16x8 af0 = *(const bf16x8*)(sA[cb][kk] + aOff);
      bf16x8 af1 = *(const bf16x8*)(sA[cb][kk] + aOff + 16 * 32);
      bf16x8 bf0 = *(const bf16x8*)(sB[cb][kk] + bOff);
      bf16x8 bf1 = *(const bf16x8*)(sB[cb][kk] + bOff + 16 * 32);
      acc[0][0] = __builtin_amdgcn_mfma_f32_16x16x32_bf16(af0, bf0, acc[0][0], 0, 0, 0);
      acc[0][1] = __builtin_amdgcn_mfma_f32_16x16x32_bf16(af0, bf1, acc[0][1], 0, 0, 0);
      acc[1][0] = __builtin_amdgcn_mfma_f32_16x16x32_bf16(af1, bf0, acc[1][0], 0, 0, 0);
      acc[1][1] = __builtin_amdgcn_mfma_f32_16x16x32_bf16(af1, bf1, acc[1][1], 0, 0, 0);
    }
    if (kt + 1 < NS) __syncthreads();
  }

#pragma unroll
  for (int ni = 0; ni < 2; ++ni) {
    int n = nBase + wx * 32 + ni * 16 + m16;
#pragma unroll
    for (int mi = 0; mi < 2; ++mi) {
      int m0 = mBase + wy * 32 + mi * 16 + quad * 4;
      floatx4 v = acc[mi][ni];
#pragma unroll
      for (int rr = 0; rr < 4; ++rr)
        C[(long)(m0 + rr) * N + n] = f2bf(v[rr]);
      if (SYM) {
        if (byy != bxx) {
          ushort4_t pkv;
#pragma unroll
          for (int rr = 0; rr < 4; ++rr) pkv[rr] = f2bf(v[rr]);
          *(ushort4_t*)(C + (long)n * N + m0) = pkv;
        }
      }
    }
  }
}

// ---------------- fused T1+ktv: per (bh, cq) c-chunk of 256 -----------------
// Stage 1: T1c[d][c] = sum_k Wk_h[d][k] * G_b[c][k]  (G symmetric -> G rows
// serve as NT B-operand; direct-global MFMA, G_b 2MB = L2-resident), bf16 to
// LDS [64][264] (2-way bank = free). Stage 2: ktvp partial [d][e] over the
// chunk vs Wv_h. cq==0 adds the rank-1 corrections. Fragment pattern is the
// verified ktv_small layout. 256 blocks; removes T1 global round-trip.
__global__ void t1ktv(const ushort_t* __restrict__ Wkbf, const ushort_t* __restrict__ Gbf,
                      const ushort_t* __restrict__ Wvbf,
                      const float* __restrict__ u, const float* __restrict__ wv_s,
                      const float* __restrict__ bk, const float* __restrict__ bv,
                      float* __restrict__ ktvp) {
  int bh = blockIdx.x, cq = blockIdx.y;  // 64 x 4
  int b = bh >> 4, h = bh & 15;
  __shared__ ushort_t sT1[64 * 264];
  int t = threadIdx.x, w = t >> 6, l = t & 63;
  int quad = l >> 4, m16 = l & 15;

  // ---- stage 1 ----
  const ushort_t* Arow = Wkbf + (long)(h * 64 + w * 16 + m16) * 1024 + quad * 8;
  const ushort_t* Brow = Gbf + ((long)b << 20) + (long)(cq * 256 + m16) * 1024 + quad * 8;
  floatx4 acc1[16] = {};
  for (int kt = 0; kt < 1024; kt += 32) {
    bf16x8 af = *(const bf16x8*)(Arow + kt);
#pragma unroll
    for (int j = 0; j < 16; ++j) {
      bf16x8 bfv = *(const bf16x8*)(Brow + (long)j * 16 * 1024 + kt);
      acc1[j] = __builtin_amdgcn_mfma_f32_16x16x32_bf16(af, bfv, acc1[j], 0, 0, 0);
    }
  }
#pragma unroll
  for (int j = 0; j < 16; ++j)
#pragma unroll
    for (int rr = 0; rr < 4; ++rr)
      sT1[(w * 16 + quad * 4 + rr) * 264 + j * 16 + m16] = f2bf(acc1[j][rr]);
  __syncthreads();

  // ---- stage 2 ----
  const ushort_t* Brow2 = Wvbf + (long)(h * 64 + m16) * 1024 + cq * 256 + quad * 8;
  floatx4 acc2[4] = {};
  for (int kt = 0; kt < 256; kt += 32) {
    bf16x8 af2 = *(const bf16x8*)(sT1 + (w * 16 + m16) * 264 + quad * 8 + kt);
#pragma unroll
    for (int j = 0; j < 4; ++j) {
      bf16x8 bfv = *(const bf16x8*)(Brow2 + (long)j * 16 * 1024 + kt);
      acc2[j] = __builtin_amdgcn_mfma_f32_16x16x32_bf16(af2, bfv, acc2[j], 0, 0, 0);
    }
  }
  float* p = ktvp + ((long)(cq * 64 + bh)) * 4096;
#pragma unroll
  for (int j = 0; j < 4; ++j) {
    int e = j * 16 + m16;
    float bve = bv[h * 64 + e];
    float wse = wv_s[b * 1024 + h * 64 + e] + 4096.f * bve;
#pragma unroll
    for (int rr = 0; rr < 4; ++rr) {
      int d = w * 16 + quad * 4 + rr;
      float corr = (cq == 0)
          ? (u[b * 1024 + h * 64 + d] * bve + bk[h * 64 + d] * wse) : 0.f;
      p[d * 64 + e] = acc2[j][rr] + corr;
    }
  }
}

// ---------------- build W2T (bf16) and bias2 (fp32) from ktv partials -------
__global__ void make_w2(const float* __restrict__ Wq, const float* __restrict__ bq,
                        const float* __restrict__ ktvp, ushort_t* __restrict__ W2T,
                        float* __restrict__ bias2, float scale) {
  int bh = blockIdx.x, cq = blockIdx.y;
  int b = bh >> 4, h = bh & 15;
  __shared__ float sKTV[64 * 64];
  __shared__ float sW[64 * 64];
  int t = threadIdx.x;
  const float* kp = ktvp + (long)bh * 4096;
  for (int i = t * 4; i < 4096; i += 1024) {
    float4 v0 = *(const float4*)(kp + i);
    float4 v1 = *(const float4*)(kp + 262144 + i);
    float4 v2 = *(const float4*)(kp + 524288 + i);
    float4 v3 = *(const float4*)(kp + 786432 + i);
    float4 s;
    s.x = v0.x + v1.x + v2.x + v3.x;
    s.y = v0.y + v1.y + v2.y + v3.y;
    s.z = v0.z + v1.z + v2.z + v3.z;
    s.w = v0.w + v1.w + v2.w + v3.w;
    *(float4*)(sKTV + i) = s;
  }
  __syncthreads();
  if (cq == 0 && t < 64) {
    float s = 0.f;
    for (int d = 0; d < 64; ++d) s += bq[h * 64 + d] * sKTV[d * 64 + t];
    bias2[b * 1024 + h * 64 + t] = s * scale;
  }
  int e = t >> 2, c0 = (t & 3) * 16;
  for (int ct = cq * 256; ct < cq * 256 + 256; ct += 64) {
    __syncthreads();
    {
      int d = t >> 2, cc = (t & 3) * 16;
#pragma unroll
      for (int j = 0; j < 16; j += 4)
        *(float4*)(sW + d * 64 + cc + j) =
            *(const float4*)(Wq + (long)(h * 64 + d) * 1024 + ct + cc + j);
    }
    __syncthreads();
    float outv[16] = {};
    for (int d = 0; d < 64; ++d) {
      float kv = sKTV[d * 64 + e];
#pragma unroll
      for (int j = 0; j < 16; ++j) outv[j] += sW[d * 64 + c0 + j] * kv;
    }
    ushort8 o0, o1;
#pragma unroll
    for (int j = 0; j < 8; ++j) { o0[j] = f2bf(outv[j] * scale); o1[j] = f2bf(outv[8 + j] * scale); }
    ushort_t* dst = W2T + ((long)(b * 1024 + h * 64 + e)) * 1024 + ct + c0;
    *(ushort8*)dst = o0;
    *(ushort8*)(dst + 8) = o1;
  }
}

// ---------------- launch -----------------------------------------------------
extern "C" void kernel_launch(void* const* d_in, const int* in_sizes, int n_in,
                              void* d_out, int out_size, void* d_ws, size_t ws_size,
                              hipStream_t stream) {
  (void)in_sizes; (void)n_in; (void)out_size; (void)ws_size;
  const float* tens = (const float*)d_in[0];
  const float* Wq = (const float*)d_in[1];
  const float* bq = (const float*)d_in[2];
  const float* Wk = (const float*)d_in[3];
  const float* bk = (const float*)d_in[4];
  const float* Wv = (const float*)d_in[5];
  const float* bv = (const float*)d_in[6];
  float* out = (float*)d_out;

  char* w = (char*)d_ws;
  ushort_t* Xbf  = (ushort_t*)(w);                    // 33,554,432 B
  ushort_t* XT   = (ushort_t*)(w + 33554432);         // 33,554,432 B
  ushort_t* Wkbf = (ushort_t*)(w + 67108864);         //  2,097,152 B
  ushort_t* Wvbf = (ushort_t*)(w + 69206016);         //  2,097,152 B
  ushort_t* Gbf  = (ushort_t*)(w + 71303168);         //  8,388,608 B
  float*    spart= (float*)(w + 79691776);            //  1,048,576 B
  float*    u    = (float*)(w + 80740352);            //     16,384 B
  float*    wv_s = (float*)(w + 80756736);            //     16,384 B
  float*    ktvp = (float*)(w + 80773120);            //  4,194,304 B
  ushort_t* W2T  = (ushort_t*)(w + 84967424);         //  8,388,608 B
  float*    bias2= (float*)(w + 93356032);            //     16,384 B

  const float scale = (1.0f / 8.0f) / 64.0f;  // 1/sqrt(DH)/sqrt(N)

  hipLaunchKernelGGL(cvt_tr, dim3(16, 64, 5), dim3(256), 0, stream,
                     tens, Xbf, XT, spart, Wk, Wkbf, Wv, Wvbf);

  // G_b = X_b^T X_b (sym lower-triangle, 544 tiles) + 32 uw blocks
  hipLaunchKernelGGL((gemm64<4096, true, true>), dim3(144, 4, 1), dim3(256), 0, stream,
                     XT, XT, Gbf, 1024, 4194304L, 4194304L, 1048576L,
                     Wkbf, Wvbf, spart, u, wv_s);

  // fused T1+ktv: ktvp[cq] partials (256 blocks)
  hipLaunchKernelGGL(t1ktv, dim3(64, 4), dim3(256), 0, stream,
                     Wkbf, Gbf, Wvbf, u, wv_s, bk, bv, ktvp);

  hipLaunchKernelGGL(make_w2, dim3(64, 4), dim3(256), 0, stream,
                     Wq, bq, ktvp, W2T, bias2, scale);

  // final: out = Xbf @ W2T^T + bias2 (256^2 minimal-sync, swapped epilogue)
  hipLaunchKernelGGL((gemm256<1024>), dim3(4, 16, 4), dim3(512), 0, stream,
                     Xbf, W2T, bias2, out, 1024,
                     4194304L, 1048576L, 1024L, 4194304L);
}

// Round 14
// 264.886 us; speedup vs baseline: 1.3609x; 1.3609x over previous
//
#include <hip/hip_runtime.h>

typedef unsigned short ushort_t;
typedef __attribute__((ext_vector_type(8))) __bf16 bf16x8;
typedef __attribute__((ext_vector_type(8))) unsigned short ushort8;
typedef __attribute__((ext_vector_type(4))) unsigned short ushort4_t;
typedef __attribute__((ext_vector_type(4))) float floatx4;

__device__ inline unsigned short f2bf(float f) {
  union { float f; unsigned u; } x; x.f = f;
  return (unsigned short)((x.u + 0x7FFFu + ((x.u >> 16) & 1u)) >> 16);
}
__device__ inline float bf2f(unsigned short v) {
  union { unsigned u; float f; } x; x.u = (unsigned)v << 16;
  return x.f;
}

__device__ inline void bar() {
  asm volatile("" ::: "memory");
  __builtin_amdgcn_s_barrier();
  asm volatile("" ::: "memory");
}
#define WAITV0 asm volatile("s_waitcnt vmcnt(0)" ::: "memory")

// ---- fused: tens fp32 -> Xbf + XT; per-block colsum partials; weight plane --
__global__ void cvt_tr(const float* __restrict__ tens, ushort_t* __restrict__ Xbf,
                       ushort_t* __restrict__ XT, float* __restrict__ spart,
                       const float* __restrict__ Wk, ushort_t* __restrict__ Wkbf,
                       const float* __restrict__ Wv, ushort_t* __restrict__ Wvbf) {
  int t = threadIdx.x;
  if (blockIdx.z == 4) {
    int flat = blockIdx.x + 16 * blockIdx.y;  // 0..1023
    const float* in; ushort_t* out;
    if (flat < 512) { in = Wk; out = Wkbf; } else { in = Wv; out = Wvbf; flat -= 512; }
    int i = (flat * 256 + t) * 8;
    const float4* p = (const float4*)(in + i);
    float4 x = p[0], y = p[1];
    ushort8 o;
    o[0] = f2bf(x.x); o[1] = f2bf(x.y); o[2] = f2bf(x.z); o[3] = f2bf(x.w);
    o[4] = f2bf(y.x); o[5] = f2bf(y.y); o[6] = f2bf(y.z); o[7] = f2bf(y.w);
    *(ushort8*)(out + i) = o;
    return;
  }
  int b = blockIdx.z;
  int d0 = blockIdx.x * 64;  // 16
  int n0 = blockIdx.y * 64;  // 64
  __shared__ ushort_t sT[64 * 72];
  int nl = t >> 2, c16 = (t & 3) * 16;
  const float* src = tens + ((long)b << 22) + (long)(n0 + nl) * 1024 + d0 + c16;
  ushort8 o0, o1;
#pragma unroll
  for (int j = 0; j < 2; ++j) {
    float4 v0 = *(const float4*)(src + j * 8);
    float4 v1 = *(const float4*)(src + j * 8 + 4);
    ushort8 o;
    o[0] = f2bf(v0.x); o[1] = f2bf(v0.y); o[2] = f2bf(v0.z); o[3] = f2bf(v0.w);
    o[4] = f2bf(v1.x); o[5] = f2bf(v1.y); o[6] = f2bf(v1.z); o[7] = f2bf(v1.w);
#pragma unroll
    for (int i = 0; i < 8; ++i) sT[(c16 + j * 8 + i) * 72 + nl] = o[i];
    if (j == 0) o0 = o; else o1 = o;
  }
  ushort_t* xdst = Xbf + ((long)b << 22) + (long)(n0 + nl) * 1024 + d0 + c16;
  *(ushort8*)xdst = o0;
  *(ushort8*)(xdst + 8) = o1;
  __syncthreads();
  int dl = t >> 2, n16 = (t & 3) * 16;
  ushort8 t0 = *(const ushort8*)(sT + dl * 72 + n16);
  ushort8 t1 = *(const ushort8*)(sT + dl * 72 + n16 + 8);
  ushort_t* dst = XT + ((long)b << 22) + (long)(d0 + dl) * 4096 + n0 + n16;
  *(ushort8*)dst = t0;
  *(ushort8*)(dst + 8) = t1;
  float ps = 0.f;
#pragma unroll
  for (int i = 0; i < 8; ++i) ps += bf2f(t0[i]) + bf2f(t1[i]);
  ps += __shfl_xor(ps, 1);
  ps += __shfl_xor(ps, 2);
  if ((t & 3) == 0) spart[(((long)b << 6) + blockIdx.y) * 1024 + d0 + dl] = ps;
}

// ---------------- async global->LDS helper ----------------------------------
__device__ inline void gload_lds16(const void* g, void* l) {
  __builtin_amdgcn_global_load_lds(
      (const __attribute__((address_space(1))) unsigned int*)g,
      (__attribute__((address_space(3))) unsigned int*)l, 16, 0, 0);
}

// ---------------- 256x256-tile NT GEMM, minimal-sync, swapped epilogue ------
// 8 waves (2M x 4N), wave tile 128x64, acc[8][4]. BK=64; 2dbuf x 64KB.
// Per K-tile: {STAGE(t+1 -> buf^1); 24 ds_read_b128 + 64 MFMA; vmcnt(0); bar}.
// (row&7) swizzle: inverse on GLOBAL source (linear gload dest, rule 21),
// forward on ds_read -- measured 0 bank conflicts (r11). MFMA operands
// SWAPPED (mfma(bfr, af)): lane holds 4 consecutive n at fixed m -> float4
// C-stores + float4 bias loads (round-8-verified; fixes 79->66MB write ampl).
template <int K>
__global__ __launch_bounds__(512, 2) void gemm256(
    const ushort_t* __restrict__ A, const ushort_t* __restrict__ Bm,
    const float* __restrict__ bias, float* __restrict__ C,
    int N, long sA_, long sB_, long sBias_, long sC_) {
  const int NT = K / 64;
  int gx = gridDim.x, gxy = gridDim.x * gridDim.y;
  int flat = blockIdx.x + gx * blockIdx.y + gxy * blockIdx.z;
  int total = gxy * gridDim.z;
  int per = total >> 3;
  int nf = (flat & 7) * per + (flat >> 3);
  int bz = nf / gxy; int rem = nf - bz * gxy;
  int by = rem / gx; int bx = rem - by * gx;

  A += (long)bz * sA_; Bm += (long)bz * sB_; C += (long)bz * sC_;
  bias += (long)bz * sBias_;

  __shared__ ushort_t sA[2][16384];  // [buf][half(8192) | row*64 | col]
  __shared__ ushort_t sB[2][16384];

  int t = threadIdx.x;
  int w = t >> 6, l = t & 63;
  int wy = w >> 2, wx = w & 3;            // 2M x 4N wave grid
  int quad = l >> 4, m16 = l & 15;
  int mBase = by * 256, nBase = bx * 256;

  int rp = w * 8 + (l >> 3);                       // 0..63 within group
  int p8 = l & 7;
  int ce = ((p8 ^ (rp & 7)) << 3);                 // inverse-swizzled src col
  const ushort_t* gAp[4]; const ushort_t* gBp[4];  // [half*2+g]
#pragma unroll
  for (int h = 0; h < 2; ++h)
#pragma unroll
    for (int g = 0; g < 2; ++g) {
      gAp[h * 2 + g] = A + (long)(mBase + h * 128 + g * 64 + rp) * K + ce;
      gBp[h * 2 + g] = Bm + (long)(nBase + h * 128 + g * 64 + rp) * K + ce;
    }

  int swz3 = m16 & 7;                              // read-side XOR key
  int aBase = wy * 8192 + m16 * 64;
  int bBase = (wx >> 1) * 8192 + ((wx & 1) * 64 + m16) * 64;

  floatx4 acc[8][4] = {};

  auto STAGE = [&](int kt, int buf) {
    int ko = kt * 64;
#pragma unroll
    for (int g = 0; g < 2; ++g) {
      gload_lds16(gAp[g] + ko,     sA[buf] + g * 4096 + w * 512);
      gload_lds16(gAp[2 + g] + ko, sA[buf] + 8192 + g * 4096 + w * 512);
      gload_lds16(gBp[g] + ko,     sB[buf] + g * 4096 + w * 512);
      gload_lds16(gBp[2 + g] + ko, sB[buf] + 8192 + g * 4096 + w * 512);
    }
  };

  STAGE(0, 0);
  WAITV0;
  bar();
  for (int kt = 0; kt < NT; ++kt) {
    int buf = kt & 1;
    if (kt + 1 < NT) STAGE(kt + 1, buf ^ 1);  // 8 loads fly under 64 MFMAs
    __builtin_amdgcn_sched_barrier(0);        // keep stage issue first
    const ushort_t* pa = sA[buf];
    const ushort_t* pb = sB[buf];
    __builtin_amdgcn_s_setprio(1);
#pragma unroll
    for (int ks = 0; ks < 2; ++ks) {
      int ct = (((ks * 4 + quad) ^ swz3) << 3);
      bf16x8 bfr[4];
#pragma unroll
      for (int ni = 0; ni < 4; ++ni)
        bfr[ni] = *(const bf16x8*)(pb + bBase + ni * 16 * 64 + ct);
#pragma unroll
      for (int mg = 0; mg < 2; ++mg) {
        bf16x8 af[4];
#pragma unroll
        for (int i = 0; i < 4; ++i)
          af[i] = *(const bf16x8*)(pa + aBase + (mg * 4 + i) * 16 * 64 + ct);
#pragma unroll
        for (int i = 0; i < 4; ++i)
#pragma unroll
          for (int ni = 0; ni < 4; ++ni)
            acc[mg * 4 + i][ni] = __builtin_amdgcn_mfma_f32_16x16x32_bf16(
                bfr[ni], af[i], acc[mg * 4 + i][ni], 0, 0, 0);
      }
    }
    __builtin_amdgcn_s_setprio(0);
    if (kt + 1 < NT) { WAITV0; }
    bar();
  }

  // swapped layout: col (m16) -> m; rows (quad*4+rr) -> 4 consecutive n
#pragma unroll
  for (int mi = 0; mi < 8; ++mi) {
    int m = mBase + wy * 128 + mi * 16 + m16;
    float* crow = C + (long)m * N;
#pragma unroll
    for (int ni = 0; ni < 4; ++ni) {
      int n0 = nBase + wx * 64 + ni * 16 + quad * 4;
      float4 bb = *(const float4*)(bias + n0);
      floatx4 v = acc[mi][ni];
      float4 o;
      o.x = v[0] + bb.x; o.y = v[1] + bb.y; o.z = v[2] + bb.z; o.w = v[3] + bb.w;
      *(float4*)(crow + n0) = o;
    }
  }
}

// ---------------- 64x64-tile NT GEMM, BK=64, round-5 schedule ---------------
// UW: grid padded to (144,4); blocks with nf>=544 run the u/wv_s dot-products.
template <int K, bool SYM, bool UW>
__global__ void gemm64(const ushort_t* __restrict__ A, const ushort_t* __restrict__ Bm,
                       ushort_t* __restrict__ C, int N, long sA_, long sB_, long sC_,
                       const ushort_t* __restrict__ Wkbf, const ushort_t* __restrict__ Wvbf,
                       const float* __restrict__ spart, float* __restrict__ u,
                       float* __restrict__ wv_s) {
  __shared__ ushort_t sA[2][2][64 * 32];  // [buf][kk][row*32]
  __shared__ ushort_t sB[2][2][64 * 32];
  int t = threadIdx.x;

  int bz, byy, bxx;
  if (SYM) {
    int flat = blockIdx.x + gridDim.x * blockIdx.y;
    int per = (gridDim.x * gridDim.y) >> 3;
    int nf = (flat & 7) * per + (flat >> 3);
    if (UW) {
      if (nf >= 544) {
        int id = nf - 544;  // 0..31
        int b = id & 3, which = (id >> 2) & 1, chunk = id >> 3;
        const ushort_t* W = which ? Wvbf : Wkbf;
        float* o = which ? wv_s : u;
        float* ss = (float*)sA;  // 4KB alias
        float4 a4 = {0.f, 0.f, 0.f, 0.f};
        const float* sp = spart + ((long)b << 16) + t * 4;
        for (int n0 = 0; n0 < 64; ++n0) {
          float4 v = *(const float4*)(sp + n0 * 1024);
          a4.x += v.x; a4.y += v.y; a4.z += v.z; a4.w += v.w;
        }
        *(float4*)(ss + t * 4) = a4;
        __syncthreads();
        int rr = chunk * 256 + t;
        const ushort_t* row = W + (long)rr * 1024;
        float acc = 0.f;
        for (int k = 0; k < 1024; k += 8) {
          ushort8 v = *(const ushort8*)(row + k);
#pragma unroll
          for (int i = 0; i < 8; ++i) acc += bf2f(v[i]) * ss[k + i];
        }
        o[b * 1024 + rr] = acc;
        return;
      }
    }
    bz = nf / 136;
    int tri = nf - bz * 136;
    byy = (int)((__fsqrt_rn(8.0f * tri + 1.0f) - 1.0f) * 0.5f);
    while ((byy + 1) * (byy + 2) / 2 <= tri) ++byy;
    while (byy * (byy + 1) / 2 > tri) --byy;
    bxx = tri - byy * (byy + 1) / 2;  // bxx <= byy
  } else {
    int gx = gridDim.x, gxy = gridDim.x * gridDim.y;
    int flat = blockIdx.x + gx * blockIdx.y + gxy * blockIdx.z;
    int total = gxy * gridDim.z;
    int per = total >> 3;
    int nf = (flat & 7) * per + (flat >> 3);
    bz = nf / gxy; int rem = nf - bz * gxy;
    byy = rem / gx; bxx = rem - byy * gx;
  }

  A += (long)bz * sA_; Bm += (long)bz * sB_; C += (long)bz * sC_;

  int w = t >> 6, l = t & 63;
  int wy = w >> 1, wx = w & 1;
  int quad = l >> 4, m16 = l & 15;
  int mBase = byy * 64, nBase = bxx * 64;

  int r = l >> 2, pk = l & 3;
  int sCol = (pk ^ ((r >> 1) & 3)) * 8;
  int sRow = w * 16 + r;
  const ushort_t* gA = A + (long)(mBase + sRow) * K + sCol;
  const ushort_t* gB = Bm + (long)(nBase + sRow) * K + sCol;
  int lOff = w * 512;

  int swzR = (m16 >> 1) & 3;
  int aOff = (wy * 32 + m16) * 32 + (quad ^ swzR) * 8;
  int bOff = (wx * 32 + m16) * 32 + (quad ^ swzR) * 8;

  floatx4 acc[2][2] = {};
  const int NS = K / 64;

#pragma unroll
  for (int kk = 0; kk < 2; ++kk) {
    gload_lds16(gA + kk * 32, sA[0][kk] + lOff);
    gload_lds16(gB + kk * 32, sB[0][kk] + lOff);
  }
  __syncthreads();

  for (int kt = 0; kt < NS; ++kt) {
    if (kt + 1 < NS) {
      int nb = (kt + 1) & 1, ko = (kt + 1) * 64;
#pragma unroll
      for (int kk = 0; kk < 2; ++kk) {
        gload_lds16(gA + ko + kk * 32, sA[nb][kk] + lOff);
        gload_lds16(gB + ko + kk * 32, sB[nb][kk] + lOff);
      }
    }
    __builtin_amdgcn_sched_barrier(0);
    int cb = kt & 1;
#pragma unroll
    for (int kk = 0; kk < 2; ++kk) {
      bf16x8 af0 = *(const bf16x8*)(sA[cb][kk] + aOff);
      bf16x8 af1 = *(const bf16x8*)(sA[cb][kk] + aOff + 16 * 32);
      bf16x8 bf0 = *(const bf16x8*)(sB[cb][kk] + bOff);
      bf16x8 bf1 = *(const bf16x8*)(sB[cb][kk] + bOff + 16 * 32);
      acc[0][0] = __builtin_amdgcn_mfma_f32_16x16x32_bf16(af0, bf0, acc[0][0], 0, 0, 0);
      acc[0][1] = __builtin_amdgcn_mfma_f32_16x16x32_bf16(af0, bf1, acc[0][1], 0, 0, 0);
      acc[1][0] = __builtin_amdgcn_mfma_f32_16x16x32_bf16(af1, bf0, acc[1][0], 0, 0, 0);
      acc[1][1] = __builtin_amdgcn_mfma_f32_16x16x32_bf16(af1, bf1, acc[1][1], 0, 0, 0);
    }
    if (kt + 1 < NS) __syncthreads();
  }

#pragma unroll
  for (int ni = 0; ni < 2; ++ni) {
    int n = nBase + wx * 32 + ni * 16 + m16;
#pragma unroll
    for (int mi = 0; mi < 2; ++mi) {
      int m0 = mBase + wy * 32 + mi * 16 + quad * 4;
      floatx4 v = acc[mi][ni];
#pragma unroll
      for (int rr = 0; rr < 4; ++rr)
        C[(long)(m0 + rr) * N + n] = f2bf(v[rr]);
      if (SYM) {
        if (byy != bxx) {
          ushort4_t pkv;
#pragma unroll
          for (int rr = 0; rr < 4; ++rr) pkv[rr] = f2bf(v[rr]);
          *(ushort4_t*)(C + (long)n * N + m0) = pkv;
        }
      }
    }
  }
}

// ---------------- ktv partials: 4-way k-split, 256 blocks -------------------
__global__ void ktv_part_k(const ushort_t* __restrict__ T1, const ushort_t* __restrict__ Wvbf,
                           const float* __restrict__ u, const float* __restrict__ wv_s,
                           const float* __restrict__ bk, const float* __restrict__ bv,
                           float* __restrict__ ktvp) {
  int id = blockIdx.x;           // 256: bh fastest for XCD spread
  int bh = id & 63, sl = id >> 6;
  int b = bh >> 4, h = bh & 15;
  int t = threadIdx.x, w = t >> 6, l = t & 63;
  int quad = l >> 4, m16 = l & 15;
  const ushort_t* Arow = T1 + ((long)b << 20) + (long)(h * 64 + w * 16 + m16) * 1024
                         + sl * 256 + quad * 8;
  const ushort_t* Brow = Wvbf + (long)(h * 64 + m16) * 1024 + sl * 256 + quad * 8;
  floatx4 acc[4] = {};
  for (int kt = 0; kt < 256; kt += 32) {
    bf16x8 af = *(const bf16x8*)(Arow + kt);
#pragma unroll
    for (int j = 0; j < 4; ++j) {
      bf16x8 bfv = *(const bf16x8*)(Brow + (long)j * 16 * 1024 + kt);
      acc[j] = __builtin_amdgcn_mfma_f32_16x16x32_bf16(af, bfv, acc[j], 0, 0, 0);
    }
  }
  float* p = ktvp + ((long)(sl * 64 + bh)) * 4096;
#pragma unroll
  for (int j = 0; j < 4; ++j) {
    int e = j * 16 + m16;
    float bve = bv[h * 64 + e];
    float wse = wv_s[b * 1024 + h * 64 + e] + 4096.f * bve;
#pragma unroll
    for (int rr = 0; rr < 4; ++rr) {
      int d = w * 16 + quad * 4 + rr;
      float corr = (sl == 0)
          ? (u[b * 1024 + h * 64 + d] * bve + bk[h * 64 + d] * wse) : 0.f;
      p[d * 64 + e] = acc[j][rr] + corr;
    }
  }
}

// ---------------- build W2T (bf16) and bias2 (fp32) from ktv partials -------
__global__ void make_w2(const float* __restrict__ Wq, const float* __restrict__ bq,
                        const float* __restrict__ ktvp, ushort_t* __restrict__ W2T,
                        float* __restrict__ bias2, float scale) {
  int bh = blockIdx.x, cq = blockIdx.y;
  int b = bh >> 4, h = bh & 15;
  __shared__ float sKTV[64 * 64];
  __shared__ float sW[64 * 64];
  int t = threadIdx.x;
  const float* kp = ktvp + (long)bh * 4096;
  for (int i = t * 4; i < 4096; i += 1024) {
    float4 v0 = *(const float4*)(kp + i);
    float4 v1 = *(const float4*)(kp + 262144 + i);
    float4 v2 = *(const float4*)(kp + 524288 + i);
    float4 v3 = *(const float4*)(kp + 786432 + i);
    float4 s;
    s.x = v0.x + v1.x + v2.x + v3.x;
    s.y = v0.y + v1.y + v2.y + v3.y;
    s.z = v0.z + v1.z + v2.z + v3.z;
    s.w = v0.w + v1.w + v2.w + v3.w;
    *(float4*)(sKTV + i) = s;
  }
  __syncthreads();
  if (cq == 0 && t < 64) {
    float s = 0.f;
    for (int d = 0; d < 64; ++d) s += bq[h * 64 + d] * sKTV[d * 64 + t];
    bias2[b * 1024 + h * 64 + t] = s * scale;
  }
  int e = t >> 2, c0 = (t & 3) * 16;
  for (int ct = cq * 256; ct < cq * 256 + 256; ct += 64) {
    __syncthreads();
    {
      int d = t >> 2, cc = (t & 3) * 16;
#pragma unroll
      for (int j = 0; j < 16; j += 4)
        *(float4*)(sW + d * 64 + cc + j) =
            *(const float4*)(Wq + (long)(h * 64 + d) * 1024 + ct + cc + j);
    }
    __syncthreads();
    float outv[16] = {};
    for (int d = 0; d < 64; ++d) {
      float kv = sKTV[d * 64 + e];
#pragma unroll
      for (int j = 0; j < 16; ++j) outv[j] += sW[d * 64 + c0 + j] * kv;
    }
    ushort8 o0, o1;
#pragma unroll
    for (int j = 0; j < 8; ++j) { o0[j] = f2bf(outv[j] * scale); o1[j] = f2bf(outv[8 + j] * scale); }
    ushort_t* dst = W2T + ((long)(b * 1024 + h * 64 + e)) * 1024 + ct + c0;
    *(ushort8*)dst = o0;
    *(ushort8*)(dst + 8) = o1;
  }
}

// ---------------- launch -----------------------------------------------------
extern "C" void kernel_launch(void* const* d_in, const int* in_sizes, int n_in,
                              void* d_out, int out_size, void* d_ws, size_t ws_size,
                              hipStream_t stream) {
  (void)in_sizes; (void)n_in; (void)out_size; (void)ws_size;
  const float* tens = (const float*)d_in[0];
  const float* Wq = (const float*)d_in[1];
  const float* bq = (const float*)d_in[2];
  const float* Wk = (const float*)d_in[3];
  const float* bk = (const float*)d_in[4];
  const float* Wv = (const float*)d_in[5];
  const float* bv = (const float*)d_in[6];
  float* out = (float*)d_out;

  char* w = (char*)d_ws;
  ushort_t* Xbf  = (ushort_t*)(w);                    // 33,554,432 B
  ushort_t* XT   = (ushort_t*)(w + 33554432);         // 33,554,432 B
  ushort_t* Wkbf = (ushort_t*)(w + 67108864);         //  2,097,152 B
  ushort_t* Wvbf = (ushort_t*)(w + 69206016);         //  2,097,152 B
  ushort_t* Gbf  = (ushort_t*)(w + 71303168);         //  8,388,608 B
  ushort_t* T1   = (ushort_t*)(w + 79691776);         //  8,388,608 B
  float*    spart= (float*)(w + 88080384);            //  1,048,576 B
  float*    u    = (float*)(w + 89128960);            //     16,384 B
  float*    wv_s = (float*)(w + 89145344);            //     16,384 B
  float*    ktvp = (float*)(w + 89161728);            //  4,194,304 B
  ushort_t* W2T  = (ushort_t*)(w + 93356032);         //  8,388,608 B
  float*    bias2= (float*)(w + 101744640);           //     16,384 B

  const float scale = (1.0f / 8.0f) / 64.0f;  // 1/sqrt(DH)/sqrt(N)

  hipLaunchKernelGGL(cvt_tr, dim3(16, 64, 5), dim3(256), 0, stream,
                     tens, Xbf, XT, spart, Wk, Wkbf, Wv, Wvbf);

  // G_b = X_b^T X_b (sym lower-triangle, 544 tiles) + 32 uw blocks
  hipLaunchKernelGGL((gemm64<4096, true, true>), dim3(144, 4, 1), dim3(256), 0, stream,
                     XT, XT, Gbf, 1024, 4194304L, 4194304L, 1048576L,
                     Wkbf, Wvbf, spart, u, wv_s);

  // T1_b = Wk * G_b
  hipLaunchKernelGGL((gemm64<1024, false, false>), dim3(16, 16, 4), dim3(256), 0, stream,
                     Wkbf, Gbf, T1, 1024, 0L, 1048576L, 1048576L,
                     (const ushort_t*)nullptr, (const ushort_t*)nullptr,
                     (const float*)nullptr, (float*)nullptr, (float*)nullptr);

  hipLaunchKernelGGL(ktv_part_k, dim3(256), dim3(256), 0, stream,
                     T1, Wvbf, u, wv_s, bk, bv, ktvp);

  hipLaunchKernelGGL(make_w2, dim3(64, 4), dim3(256), 0, stream,
                     Wq, bq, ktvp, W2T, bias2, scale);

  // final: out = Xbf @ W2T^T + bias2 (256^2 minimal-sync, swapped epilogue)
  hipLaunchKernelGGL((gemm256<1024>), dim3(4, 16, 4), dim3(512), 0, stream,
                     Xbf, W2T, bias2, out, 1024,
                     4194304L, 1048576L, 1024L, 4194304L);
}